// Round 3
// baseline (491.189 us; speedup 1.0000x reference)
//
#include <hip/hip_runtime.h>

// Problem constants
#define DIM_   512
#define NSEQ   1024
#define BB     16
#define HH     16
#define KD_    32
#define DD_    128
#define LDQKV  3072   // H*(2*KD+D)
#define DH_    2048   // H*D
#define SCALE_ 0.17677669529663687f  // 32^-0.5

typedef __bf16 bf16x8 __attribute__((ext_vector_type(8)));
typedef float  f32x4  __attribute__((ext_vector_type(4)));
typedef unsigned int u32x4v __attribute__((ext_vector_type(4)));

typedef __attribute__((address_space(1))) const unsigned int guint;
typedef __attribute__((address_space(3))) unsigned int luint;
#define GLL16(gp, lp) __builtin_amdgcn_global_load_lds((guint*)(gp), (luint*)(lp), 16, 0, 0)

static __device__ __forceinline__ unsigned short f2bf(float f) {
  unsigned int u = __builtin_bit_cast(unsigned int, f);
  u += 0x7fffu + ((u >> 16) & 1u);   // round-to-nearest-even
  return (unsigned short)(u >> 16);
}
// key-within-group permutation (v5 HW-verified), matched between P-order and V reads.
#define SGM(t) ((((t) & 3) << 1) | (((t) >> 2) & 1))

// ---------------- fp32 -> bf16 convert ----------------
__global__ __launch_bounds__(256) void cvt_kernel(const float* __restrict__ in,
                                                  unsigned short* __restrict__ out,
                                                  int n) {
  int i = blockIdx.x * 256 + threadIdx.x;
  if (i < n) out[i] = f2bf(in[i]);
}

// ---------------- LayerNorm (fp32 in) -> bf16 out ----------------
__global__ __launch_bounds__(256) void ln_kernel(const float* __restrict__ x,
                                                 const float* __restrict__ gamma,
                                                 const float* __restrict__ beta,
                                                 unsigned short* __restrict__ xn) {
  int row = blockIdx.x, t = threadIdx.x;
  const float* xr = x + (size_t)row * DIM_;
  float2 v = *(const float2*)(xr + t * 2);
  float s = v.x + v.y, sq = v.x * v.x + v.y * v.y;
#pragma unroll
  for (int off = 32; off; off >>= 1) {
    s  += __shfl_xor(s, off, 64);
    sq += __shfl_xor(sq, off, 64);
  }
  __shared__ float red[8];
  int wid = t >> 6, lane = t & 63;
  if (lane == 0) { red[wid * 2] = s; red[wid * 2 + 1] = sq; }
  __syncthreads();
  float S  = red[0] + red[2] + red[4] + red[6];
  float SQ = red[1] + red[3] + red[5] + red[7];
  float mu   = S * (1.f / DIM_);
  float var  = SQ * (1.f / DIM_) - mu * mu;
  float rstd = rsqrtf(var + 1e-5f);
  int c = t * 2;
  xn[(size_t)row * DIM_ + c]     = f2bf((v.x - mu) * rstd * gamma[c]     + beta[c]);
  xn[(size_t)row * DIM_ + c + 1] = f2bf((v.y - mu) * rstd * gamma[c + 1] + beta[c + 1]);
}

// ---------------- GEMM (GLL staging, bf16/fp32 out): C = A*W^T + bias ----------------
template <typename OUT>
__global__ __launch_bounds__(256) void gemm_gll(const unsigned short* __restrict__ A, int lda,
                                                const unsigned short* __restrict__ W, int ldb,
                                                const float* __restrict__ bias,
                                                OUT* __restrict__ C, int ldc,
                                                int K) {
  __shared__ unsigned short a_sm[128][64];
  __shared__ unsigned short b_sm[128][64];
  int tid = threadIdx.x;
  int lane = tid & 63, w = tid >> 6;
  int quad = lane >> 4, l15 = lane & 15;
  int wr = w >> 1, wc = w & 1;
  long tm = (long)blockIdx.y * 128, tn = (long)blockIdx.x * 128;
  int srow = w * 8 + (lane >> 3), scol = (lane & 7) * 8;

  f32x4 acc[4][4] = {};

  for (int k0 = 0; k0 < K; k0 += 64) {
    __syncthreads();
#pragma unroll
    for (int it = 0; it < 4; it++) {
      GLL16(A + (tm + it * 32 + srow) * lda + k0 + scol, &a_sm[it * 32 + w * 8][0]);
      GLL16(W + (tn + it * 32 + srow) * ldb + k0 + scol, &b_sm[it * 32 + w * 8][0]);
    }
    __syncthreads();
#pragma unroll
    for (int kk = 0; kk < 64; kk += 32) {
      bf16x8 af[4], bfr[4];
#pragma unroll
      for (int i = 0; i < 4; i++)
        af[i] = *(const bf16x8*)&a_sm[wr * 64 + i * 16 + l15][kk + quad * 8];
#pragma unroll
      for (int j = 0; j < 4; j++)
        bfr[j] = *(const bf16x8*)&b_sm[wc * 64 + j * 16 + l15][kk + quad * 8];
#pragma unroll
      for (int i = 0; i < 4; i++)
#pragma unroll
        for (int j = 0; j < 4; j++)
          acc[i][j] = __builtin_amdgcn_mfma_f32_16x16x32_bf16(af[i], bfr[j], acc[i][j], 0, 0, 0);
    }
  }
#pragma unroll
  for (int j = 0; j < 4; j++) {
    long col = tn + wc * 64 + j * 16 + l15;
    float bv = bias[col];
#pragma unroll
    for (int i = 0; i < 4; i++) {
      long row0 = tm + wr * 64 + i * 16 + quad * 4;
#pragma unroll
      for (int r = 0; r < 4; r++) {
        float val = acc[i][j][r] + bv;
        if constexpr (__is_same(OUT, float))
          C[(row0 + r) * ldc + col] = val;
        else
          C[(row0 + r) * ldc + col] = f2bf(val);
      }
    }
  }
}

// ---------------- Flash attention v8: v5 V-path + swapped QK^T + in-reg P ------------
// Keeps v5's HW-verified V machinery (SGM-swizzled vt tile, b128 reads).
// Per 64-key tile, wave w owns q rows w*16..+16:
//   S^T = mfma(K, Q): lane (quad,l15) holds st[nb][r] = P[q=l15][key=16nb+4quad+r]
//   bias hoisted: dy_pre[8] per lane, dx = 2 values/tile
//   P redistributed in-register via ds_bpermute (receiver-side selects), in the
//   SGM element order v5's vt reads require: A word jj = keys {8g+jj, 8g+jj+4}
//   p_sm round-trip and its barrier are gone (2 barriers/tile).
__global__ __launch_bounds__(256) void attn_kernel(const unsigned short* __restrict__ qkv,
                                                   const float* __restrict__ ab,
                                                   unsigned short* __restrict__ attn_out) {
  __shared__ float lut[1024];
  __shared__ unsigned short vt[128][72];      // V^T tile, SGM-swizzled cols (v5 layout)
  __shared__ unsigned short k_sm[64][40];

  int tid = threadIdx.x;
  int lane = tid & 63, w = tid >> 6;
  int quad = lane >> 4, l15 = lane & 15;

  // XCD-grouped decode: id%8 selects XCD; 16 consecutive ids on one XCD share (b,h)
  int id = blockIdx.x;
  int bh = ((id >> 7) << 3) | (id & 7);
  int qb = (id >> 3) & 15;
  int b = bh >> 4, h = bh & 15;
  const unsigned short* base = qkv + (size_t)b * NSEQ * LDQKV + h * 192;

  for (int t = tid; t < 1024; t += 256) lut[t] = ab[h * 1024 + t];

  // Q fragment (B-operand of swapped QK^T): lane holds Q[q = w*16+l15][kd = quad*8+j]
  int qg = qb * 64 + w * 16 + l15;
  bf16x8 qf = *(const bf16x8*)(base + (size_t)qg * LDQKV + quad * 8);

  // bias geometry (hoisted): rx,ry lane-constant; dy depends only on (nb&1, r)
  int rx = qg >> 5, ry = qg & 31;
  int dy_pre[8];
#pragma unroll
  for (int i = 0; i < 8; i++) {
    int cy = ((i >> 2) << 4) | (quad * 4 + (i & 3));
    int d = ry - cy; dy_pre[i] = d < 0 ? -d : d;
  }

  int ixA = ((quad & 1) * 32 + l15) * 4;   // bpermute byte idx: source quad 2*(quad&1)
  int ixB = ixA + 64;                      // source quad 2*(quad&1)+1
  bool hiq = quad >= 2;                    // receiver-side slot select (nb = 2kc + (quad>>1))

  f32x4 accO[8] = {};
  float l_r = 0.f;

  int kkey = tid >> 2, kch = tid & 3;

  // prologue prefetch (tile 0) — v5 pattern
  uint4 vreg[4];
  uint4 kreg;
#pragma unroll
  for (int i = 0; i < 4; i++) {
    int c = tid + i * 256;
    int m = c >> 4, c8 = c & 15;
    vreg[i] = *(const uint4*)(base + (size_t)m * LDQKV + 64 + c8 * 8);
  }
  kreg = *(const uint4*)(base + (size_t)kkey * LDQKV + 32 + kch * 8);

  for (int kt = 0; kt < 16; kt++) {
    __syncthreads();  // prior tile's readers done
    // stage regs -> LDS (v5's SGM scatter for V^T; b128 for K)
#pragma unroll
    for (int i = 0; i < 4; i++) {
      int c = tid + i * 256;
      int m = c >> 4, c8 = c & 15;
      const unsigned short* pv = (const unsigned short*)&vreg[i];
      int col = (((m >> 3) ^ (c8 & 7)) << 3) | SGM(m & 7);
#pragma unroll
      for (int e = 0; e < 8; e++) vt[c8 * 8 + e][col] = pv[e];
    }
    *(uint4*)&k_sm[kkey][kch * 8] = kreg;
    __syncthreads();  // staged

    if (kt < 15) {
#pragma unroll
      for (int i = 0; i < 4; i++) {
        int c = tid + i * 256;
        int m = c >> 4, c8 = c & 15;
        vreg[i] = *(const uint4*)(base + (size_t)((kt + 1) * 64 + m) * LDQKV + 64 + c8 * 8);
      }
      kreg = *(const uint4*)(base + (size_t)((kt + 1) * 64 + kkey) * LDQKV + 32 + kch * 8);
    }

    // S^T = K Q^T : lane holds st[nb][r] = S[q = w*16+l15][key = 16nb + 4quad + r]
    f32x4 st[4];
#pragma unroll
    for (int nb = 0; nb < 4; nb++) {
      bf16x8 kf = *(const bf16x8*)&k_sm[nb * 16 + l15][quad * 8];
      f32x4 z = {};
      st[nb] = __builtin_amdgcn_mfma_f32_16x16x32_bf16(kf, qf, z, 0, 0, 0);
    }

    // bias + exp in regs; pack pk[nb*2+t] = {bf16 st[nb][2t], bf16 st[nb][2t+1]}
    int d0 = rx - 2 * kt;     int dxa = d0 < 0 ? -d0 : d0;
    int d1 = d0 - 1;          int dxb = d1 < 0 ? -d1 : d1;
    int lb0 = dxa << 5, lb1 = dxb << 5;

    unsigned pk[8];
#pragma unroll
    for (int nb = 0; nb < 4; nb++) {
      int lb = (nb & 2) ? lb1 : lb0;
#pragma unroll
      for (int t = 0; t < 2; t++) {
        float p0 = __expf(fmaf(st[nb][2 * t],     SCALE_, lut[lb + dy_pre[(nb & 1) * 4 + 2 * t]]));
        float p1 = __expf(fmaf(st[nb][2 * t + 1], SCALE_, lut[lb + dy_pre[(nb & 1) * 4 + 2 * t + 1]]));
        l_r += p0 + p1;
        unsigned short u0 = __builtin_bit_cast(unsigned short, (__bf16)p0);
        unsigned short u1 = __builtin_bit_cast(unsigned short, (__bf16)p1);
        pk[nb * 2 + t] = (unsigned)u0 | ((unsigned)u1 << 16);
      }
    }

    // O += P V.  A-frag word jj (= elems 2jj,2jj+1) must hold keys {8g+jj, 8g+jj+4},
    // g = kc*4 + quad  (matches v5's SGM^-1 order of the vt b128 read).
    // st[nb][jj] with nb = 2kc+(quad>>1): lo16 from source quad 2*(quad&1) (ixA),
    // hi16 from source quad 2*(quad&1)+1 (ixB); slot pk[4kc+2*(quad>>1)+(jj>>1)], half jj&1.
#pragma unroll
    for (int kc = 0; kc < 2; kc++) {
      int s0 = (int)pk[4 * kc + 0], s1 = (int)pk[4 * kc + 1];
      int s2 = (int)pk[4 * kc + 2], s3 = (int)pk[4 * kc + 3];
      unsigned a0 = (unsigned)__builtin_amdgcn_ds_bpermute(ixA, s0);
      unsigned a1 = (unsigned)__builtin_amdgcn_ds_bpermute(ixA, s1);
      unsigned a2 = (unsigned)__builtin_amdgcn_ds_bpermute(ixA, s2);
      unsigned a3 = (unsigned)__builtin_amdgcn_ds_bpermute(ixA, s3);
      unsigned b0 = (unsigned)__builtin_amdgcn_ds_bpermute(ixB, s0);
      unsigned b1 = (unsigned)__builtin_amdgcn_ds_bpermute(ixB, s1);
      unsigned b2 = (unsigned)__builtin_amdgcn_ds_bpermute(ixB, s2);
      unsigned b3 = (unsigned)__builtin_amdgcn_ds_bpermute(ixB, s3);
      unsigned u0 = hiq ? a2 : a0;   // slot 4kc + 2*(quad>>1) + 0, src quad 2*(quad&1)
      unsigned u1 = hiq ? a3 : a1;   // slot +1
      unsigned v0 = hiq ? b2 : b0;   // same slots, src quad 2*(quad&1)+1
      unsigned v1 = hiq ? b3 : b1;
      u32x4v paw;
      paw.x = (u0 & 0xffffu) | (v0 << 16);            // jj=0: keys +0 (lo), +4 (hi)
      paw.y = (u0 >> 16)     | (v0 & 0xffff0000u);    // jj=1: keys +1, +5
      paw.z = (u1 & 0xffffu) | (v1 << 16);            // jj=2: keys +2, +6
      paw.w = (u1 >> 16)     | (v1 & 0xffff0000u);    // jj=3: keys +3, +7
      bf16x8 paf = __builtin_bit_cast(bf16x8, paw);

#pragma unroll
      for (int db = 0; db < 8; db++) {
        int f = (db * 2 + (l15 >> 3)) & 7;
        int colb = ((kc * 4 + quad) ^ f) << 3;
        bf16x8 vf = *(const bf16x8*)&vt[db * 16 + l15][colb];
        accO[db] = __builtin_amdgcn_mfma_f32_16x16x32_bf16(paf, vf, accO[db], 0, 0, 0);
      }
    }
  }

  // full row-sum for q = l15: reduce partials across the 4 quads
  l_r += __shfl_xor(l_r, 16, 64);
  l_r += __shfl_xor(l_r, 32, 64);

  // epilogue: accO[db][r] = O[q-rel = quad*4 + r][d = db*16 + l15]
#pragma unroll
  for (int r = 0; r < 4; r++) {
    float lr = __shfl(l_r, quad * 4 + r, 16);
    float inv = 1.f / lr;
    int row = qb * 64 + w * 16 + quad * 4 + r;
    size_t obase = ((size_t)b * NSEQ + row) * DH_ + h * DD_;
#pragma unroll
    for (int db = 0; db < 8; db++)
      attn_out[obase + db * 16 + l15] = f2bf(accO[db][r] * inv);
  }
}

extern "C" void kernel_launch(void* const* d_in, const int* in_sizes, int n_in,
                              void* d_out, int out_size, void* d_ws, size_t ws_size,
                              hipStream_t stream) {
  const float* x      = (const float*)d_in[0];
  const float* gamma  = (const float*)d_in[1];
  const float* beta   = (const float*)d_in[2];
  const float* qkv_w  = (const float*)d_in[3];
  const float* qkv_b  = (const float*)d_in[4];
  const float* proj_w = (const float*)d_in[5];
  const float* proj_b = (const float*)d_in[6];
  const float* ab     = (const float*)d_in[7];

  char* ws = (char*)d_ws;
  unsigned short* xn      = (unsigned short*)(ws);                          // 16 MiB @0
  unsigned short* wqkv    = (unsigned short*)(ws + (size_t)16 * 1048576);   //  3 MiB @16
  unsigned short* wproj   = (unsigned short*)(ws + (size_t)19 * 1048576);   //  2 MiB @19
  unsigned short* qkv     = (unsigned short*)(ws + (size_t)21 * 1048576);   // 96 MiB @21
  unsigned short* attnout = (unsigned short*)(ws + (size_t)117 * 1048576);  // 64 MiB @117
  float* out = (float*)d_out;                                               // fp32 output

  cvt_kernel<<<dim3(6144), dim3(256), 0, stream>>>(qkv_w, wqkv, 3072 * 512);
  cvt_kernel<<<dim3(4096), dim3(256), 0, stream>>>(proj_w, wproj, 512 * 2048);
  ln_kernel<<<dim3(16384), dim3(256), 0, stream>>>(x, gamma, beta, xn);
  gemm_gll<unsigned short><<<dim3(24, 128), dim3(256), 0, stream>>>(xn, 512, wqkv, 512, qkv_b, qkv, 3072, 512);
  attn_kernel<<<dim3(4096), dim3(256), 0, stream>>>(qkv, ab, attnout);
  gemm_gll<float><<<dim3(4, 128), dim3(256), 0, stream>>>(attnout, 2048, wproj, 2048, proj_b, out, 512, 2048);
}

// Round 4
// 449.509 us; speedup vs baseline: 1.0927x; 1.0927x over previous
//
#include <hip/hip_runtime.h>

// Problem constants
#define DIM_   512
#define NSEQ   1024
#define BB     16
#define HH     16
#define KD_    32
#define DD_    128
#define LDQKV  3072   // H*(2*KD+D)
#define DH_    2048   // H*D
#define SCALE_ 0.17677669529663687f  // 32^-0.5

typedef __bf16 bf16x8 __attribute__((ext_vector_type(8)));
typedef float  f32x4  __attribute__((ext_vector_type(4)));
typedef unsigned int u32x4v __attribute__((ext_vector_type(4)));

typedef __attribute__((address_space(1))) const unsigned int guint;
typedef __attribute__((address_space(3))) unsigned int luint;
#define GLL16(gp, lp) __builtin_amdgcn_global_load_lds((guint*)(gp), (luint*)(lp), 16, 0, 0)

static __device__ __forceinline__ unsigned short f2bf(float f) {
  unsigned int u = __builtin_bit_cast(unsigned int, f);
  u += 0x7fffu + ((u >> 16) & 1u);   // round-to-nearest-even
  return (unsigned short)(u >> 16);
}

// ---------------- fp32 -> bf16 convert ----------------
__global__ __launch_bounds__(256) void cvt_kernel(const float* __restrict__ in,
                                                  unsigned short* __restrict__ out,
                                                  int n) {
  int i = blockIdx.x * 256 + threadIdx.x;
  if (i < n) out[i] = f2bf(in[i]);
}

// ---------------- LayerNorm (fp32 in) -> bf16 out ----------------
__global__ __launch_bounds__(256) void ln_kernel(const float* __restrict__ x,
                                                 const float* __restrict__ gamma,
                                                 const float* __restrict__ beta,
                                                 unsigned short* __restrict__ xn) {
  int row = blockIdx.x, t = threadIdx.x;
  const float* xr = x + (size_t)row * DIM_;
  float2 v = *(const float2*)(xr + t * 2);
  float s = v.x + v.y, sq = v.x * v.x + v.y * v.y;
#pragma unroll
  for (int off = 32; off; off >>= 1) {
    s  += __shfl_xor(s, off, 64);
    sq += __shfl_xor(sq, off, 64);
  }
  __shared__ float red[8];
  int wid = t >> 6, lane = t & 63;
  if (lane == 0) { red[wid * 2] = s; red[wid * 2 + 1] = sq; }
  __syncthreads();
  float S  = red[0] + red[2] + red[4] + red[6];
  float SQ = red[1] + red[3] + red[5] + red[7];
  float mu   = S * (1.f / DIM_);
  float var  = SQ * (1.f / DIM_) - mu * mu;
  float rstd = rsqrtf(var + 1e-5f);
  int c = t * 2;
  xn[(size_t)row * DIM_ + c]     = f2bf((v.x - mu) * rstd * gamma[c]     + beta[c]);
  xn[(size_t)row * DIM_ + c + 1] = f2bf((v.y - mu) * rstd * gamma[c + 1] + beta[c + 1]);
}

// ---------------- GEMM (GLL staging, bf16/fp32 out): C = A*W^T + bias ----------------
// VREMAP: A is the qkv buffer; logical col k' = h*128+d lives at h*192+64+d (V/O slots).
template <typename OUT, bool VREMAP>
__global__ __launch_bounds__(256) void gemm_gll(const unsigned short* __restrict__ A, int lda,
                                                const unsigned short* __restrict__ W, int ldb,
                                                const float* __restrict__ bias,
                                                OUT* __restrict__ C, int ldc,
                                                int K) {
  __shared__ unsigned short a_sm[128][64];
  __shared__ unsigned short b_sm[128][64];
  int tid = threadIdx.x;
  int lane = tid & 63, w = tid >> 6;
  int quad = lane >> 4, l15 = lane & 15;
  int wr = w >> 1, wc = w & 1;
  long tm = (long)blockIdx.y * 128, tn = (long)blockIdx.x * 128;
  int srow = w * 8 + (lane >> 3), scol = (lane & 7) * 8;

  f32x4 acc[4][4] = {};

  for (int k0 = 0; k0 < K; k0 += 64) {
    __syncthreads();
#pragma unroll
    for (int it = 0; it < 4; it++) {
      if constexpr (VREMAP) {
        int kk = k0 + scol;  // 8-chunks never straddle a 128 boundary
        GLL16(A + (size_t)(tm + it * 32 + srow) * LDQKV + (kk >> 7) * 192 + 64 + (kk & 127),
              &a_sm[it * 32 + w * 8][0]);
      } else {
        GLL16(A + (tm + it * 32 + srow) * lda + k0 + scol, &a_sm[it * 32 + w * 8][0]);
      }
      GLL16(W + (tn + it * 32 + srow) * ldb + k0 + scol, &b_sm[it * 32 + w * 8][0]);
    }
    __syncthreads();
#pragma unroll
    for (int kk = 0; kk < 64; kk += 32) {
      bf16x8 af[4], bfr[4];
#pragma unroll
      for (int i = 0; i < 4; i++)
        af[i] = *(const bf16x8*)&a_sm[wr * 64 + i * 16 + l15][kk + quad * 8];
#pragma unroll
      for (int j = 0; j < 4; j++)
        bfr[j] = *(const bf16x8*)&b_sm[wc * 64 + j * 16 + l15][kk + quad * 8];
#pragma unroll
      for (int i = 0; i < 4; i++)
#pragma unroll
        for (int j = 0; j < 4; j++)
          acc[i][j] = __builtin_amdgcn_mfma_f32_16x16x32_bf16(af[i], bfr[j], acc[i][j], 0, 0, 0);
    }
  }
#pragma unroll
  for (int j = 0; j < 4; j++) {
    long col = tn + wc * 64 + j * 16 + l15;
    float bv = bias[col];
#pragma unroll
    for (int i = 0; i < 4; i++) {
      long row0 = tm + wr * 64 + i * 16 + quad * 4;
#pragma unroll
      for (int r = 0; r < 4; r++) {
        float val = acc[i][j][r] + bv;
        if constexpr (__is_same(OUT, float))
          C[(row0 + r) * ldc + col] = val;
        else
          C[(row0 + r) * ldc + col] = f2bf(val);
      }
    }
  }
}

// ---------------- V transpose: qkv V-cols -> vT[bh][d=128][n=1024] (plain) ------------
// One-shot: pays the scatter ONCE per element instead of 16x inside attention.
__global__ __launch_bounds__(256) void transpose_v(const unsigned short* __restrict__ qkv,
                                                   unsigned short* __restrict__ vT) {
  __shared__ unsigned short lt[128][64];   // internal col-swizzle: n ^ 8*((d>>3)&7)
  int tid = threadIdx.x;
  int nt = blockIdx.x, bh = blockIdx.y;
  int b = bh >> 4, h = bh & 15;
  const unsigned short* src = qkv + ((size_t)b * NSEQ + nt * 64) * LDQKV + h * 192 + 64;
#pragma unroll
  for (int i = 0; i < 4; i++) {
    int u = tid + 256 * i;
    int nl = u >> 4, d8 = u & 15;
    uint4 r = *(const uint4*)(src + (size_t)nl * LDQKV + d8 * 8);
    const unsigned short* pr = (const unsigned short*)&r;
#pragma unroll
    for (int e = 0; e < 8; e++)
      lt[d8 * 8 + e][nl ^ ((d8 & 7) * 8)] = pr[e];
  }
  __syncthreads();
  unsigned short* dst = vT + (size_t)bh * 131072 + nt * 64;
#pragma unroll
  for (int i = 0; i < 4; i++) {
    int u = tid + 256 * i;
    int d = u >> 3, p = u & 7;
    int ct = p ^ ((d >> 3) & 7);   // stored chunk at pos p is true chunk p^s
    *(uint4*)(dst + (size_t)d * 1024 + ct * 8) = *(const uint4*)&lt[d][p * 8];
  }
}

// ---------------- Flash attention v9: GLL-staged K & pre-transposed V ----------------
// Per 64-key tile, wave w owns q rows w*16..+16:
//   V staged from vT via global_load_lds, source pre-swizzled chunk c^(d&7) (m173);
//   K staged via global_load_lds, linear [64][32]; zero scatter, zero staging VALU.
//   S^T = mfma(K, Q); bias/exp in regs; P redistributed via 8 ds_bpermute + receiver-
//   side selects (plain key order -> A word jj = keys {8g+2jj, 8g+2jj+1}, no merging).
//   O written into the (dead) V columns of qkv; GEMM2 reads them via VREMAP.
__global__ __launch_bounds__(256) void attn_kernel(const unsigned short* __restrict__ qkv,
                                                   const unsigned short* __restrict__ vT,
                                                   const float* __restrict__ ab,
                                                   unsigned short* attn_out) {
  __shared__ float lut[1024];
  __shared__ unsigned short v_sm[128][64];   // [d][key-chunk pos], pos = g ^ (d&7)
  __shared__ unsigned short k_sm[64][32];    // [key][kd] linear

  int tid = threadIdx.x;
  int lane = tid & 63, w = tid >> 6;
  int quad = lane >> 4, l15 = lane & 15;

  // XCD-grouped decode: id%8 selects XCD; 16 consecutive ids on one XCD share (b,h)
  int id = blockIdx.x;
  int bh = ((id >> 7) << 3) | (id & 7);
  int qb = (id >> 3) & 15;
  int b = bh >> 4, h = bh & 15;
  const unsigned short* base = qkv + (size_t)b * NSEQ * LDQKV + h * 192;
  const unsigned short* vTh = vT + (size_t)bh * 131072;

  for (int t = tid; t < 1024; t += 256) lut[t] = ab[h * 1024 + t];

  // Q fragment (B-operand of swapped QK^T): lane holds Q[q = w*16+l15][kd = quad*8+j]
  int qg = qb * 64 + w * 16 + l15;
  bf16x8 qf = *(const bf16x8*)(base + (size_t)qg * LDQKV + quad * 8);

  // bias geometry (hoisted)
  int rx = qg >> 5, ry = qg & 31;
  int dy_pre[8];
#pragma unroll
  for (int i = 0; i < 8; i++) {
    int cy = ((i >> 2) << 4) | (quad * 4 + (i & 3));
    int d = ry - cy; dy_pre[i] = d < 0 ? -d : d;
  }

  int ixA = ((quad & 1) * 32 + l15) * 4;   // bpermute: source quad 2*(quad&1)
  int ixB = ixA + 64;                      // source quad 2*(quad&1)+1
  bool hiq = quad >= 2;

  f32x4 accO[8] = {};
  float l_r = 0.f;

  // staging lane-constants
  int vrow   = lane >> 3;                  // d within 8-row group; d&7 == lane>>3
  int vchunk = (lane & 7) ^ (lane >> 3);   // pre-swizzled source chunk
  int krow   = w * 16 + (lane >> 2);
  int kcol   = (lane & 3) * 8;

  for (int kt = 0; kt < 16; kt++) {
    __syncthreads();   // prior tile's readers done (first iter: lut staged)
#pragma unroll
    for (int i = 0; i < 4; i++) {
      int r0 = (w * 4 + i) * 8;
      GLL16(vTh + (size_t)(r0 + vrow) * 1024 + kt * 64 + vchunk * 8, &v_sm[r0][0]);
    }
    GLL16(base + (size_t)(kt * 64 + krow) * LDQKV + 32 + kcol, &k_sm[w * 16][0]);
    asm volatile("s_waitcnt vmcnt(0)");
    __syncthreads();   // staged

    // S^T = K Q^T : lane holds st[nb][r] = S[q = w*16+l15][key = 16nb + 4quad + r]
    f32x4 st[4];
#pragma unroll
    for (int nb = 0; nb < 4; nb++) {
      bf16x8 kf = *(const bf16x8*)&k_sm[nb * 16 + l15][quad * 8];
      f32x4 z = {};
      st[nb] = __builtin_amdgcn_mfma_f32_16x16x32_bf16(kf, qf, z, 0, 0, 0);
    }

    // bias + exp in regs; pk[nb*2+t] = {bf16 st[nb][2t] lo, bf16 st[nb][2t+1] hi}
    int d0 = rx - 2 * kt;     int dxa = d0 < 0 ? -d0 : d0;
    int d1 = d0 - 1;          int dxb = d1 < 0 ? -d1 : d1;
    int lb0 = dxa << 5, lb1 = dxb << 5;

    unsigned pk[8];
#pragma unroll
    for (int nb = 0; nb < 4; nb++) {
      int lb = (nb & 2) ? lb1 : lb0;
#pragma unroll
      for (int t = 0; t < 2; t++) {
        float p0 = __expf(fmaf(st[nb][2 * t],     SCALE_, lut[lb + dy_pre[(nb & 1) * 4 + 2 * t]]));
        float p1 = __expf(fmaf(st[nb][2 * t + 1], SCALE_, lut[lb + dy_pre[(nb & 1) * 4 + 2 * t + 1]]));
        l_r += p0 + p1;
        unsigned short u0 = __builtin_bit_cast(unsigned short, (__bf16)p0);
        unsigned short u1 = __builtin_bit_cast(unsigned short, (__bf16)p1);
        pk[nb * 2 + t] = (unsigned)u0 | ((unsigned)u1 << 16);
      }
    }

    // O += P V. Plain key order: A word jj = keys {8*quad + 2jj, +1} of chunk kc
    //   = pk[4kc + 2*(quad>>1) + (jj&1)] pulled whole from src quad 2*(quad&1)+(jj>>1).
#pragma unroll
    for (int kc = 0; kc < 2; kc++) {
      int s0 = (int)pk[4 * kc + 0], s1 = (int)pk[4 * kc + 1];
      int s2 = (int)pk[4 * kc + 2], s3 = (int)pk[4 * kc + 3];
      unsigned a0 = (unsigned)__builtin_amdgcn_ds_bpermute(ixA, s0);
      unsigned a1 = (unsigned)__builtin_amdgcn_ds_bpermute(ixA, s1);
      unsigned a2 = (unsigned)__builtin_amdgcn_ds_bpermute(ixA, s2);
      unsigned a3 = (unsigned)__builtin_amdgcn_ds_bpermute(ixA, s3);
      unsigned b0 = (unsigned)__builtin_amdgcn_ds_bpermute(ixB, s0);
      unsigned b1 = (unsigned)__builtin_amdgcn_ds_bpermute(ixB, s1);
      unsigned b2 = (unsigned)__builtin_amdgcn_ds_bpermute(ixB, s2);
      unsigned b3 = (unsigned)__builtin_amdgcn_ds_bpermute(ixB, s3);
      u32x4v paw;
      paw.x = hiq ? a2 : a0;   // jj=0: keys 8q+0,1
      paw.y = hiq ? a3 : a1;   // jj=1: keys 8q+2,3
      paw.z = hiq ? b2 : b0;   // jj=2: keys 8q+4,5
      paw.w = hiq ? b3 : b1;   // jj=3: keys 8q+6,7
      bf16x8 paf = __builtin_bit_cast(bf16x8, paw);

#pragma unroll
      for (int db = 0; db < 8; db++) {
        bf16x8 vf = *(const bf16x8*)&v_sm[db * 16 + l15][((kc * 4 + quad) ^ (l15 & 7)) * 8];
        accO[db] = __builtin_amdgcn_mfma_f32_16x16x32_bf16(paf, vf, accO[db], 0, 0, 0);
      }
    }
  }

  // full row-sum for q = l15: reduce partials across the 4 quads
  l_r += __shfl_xor(l_r, 16, 64);
  l_r += __shfl_xor(l_r, 32, 64);

  // epilogue: accO[db][r] = O[q-rel = quad*4 + r][d = db*16 + l15]
  // write into qkv's V columns (dead now): row-major [b][n][h*192+64+d]
#pragma unroll
  for (int r = 0; r < 4; r++) {
    float lr = __shfl(l_r, quad * 4 + r, 16);
    float inv = 1.f / lr;
    int row = qb * 64 + w * 16 + quad * 4 + r;
    size_t obase = ((size_t)b * NSEQ + row) * LDQKV + h * 192 + 64;
#pragma unroll
    for (int db = 0; db < 8; db++)
      attn_out[obase + db * 16 + l15] = f2bf(accO[db][r] * inv);
  }
}

extern "C" void kernel_launch(void* const* d_in, const int* in_sizes, int n_in,
                              void* d_out, int out_size, void* d_ws, size_t ws_size,
                              hipStream_t stream) {
  const float* x      = (const float*)d_in[0];
  const float* gamma  = (const float*)d_in[1];
  const float* beta   = (const float*)d_in[2];
  const float* qkv_w  = (const float*)d_in[3];
  const float* qkv_b  = (const float*)d_in[4];
  const float* proj_w = (const float*)d_in[5];
  const float* proj_b = (const float*)d_in[6];
  const float* ab     = (const float*)d_in[7];

  char* ws = (char*)d_ws;
  unsigned short* xn    = (unsigned short*)(ws);                          // 16 MiB @0
  unsigned short* wqkv  = (unsigned short*)(ws + (size_t)16 * 1048576);   //  3 MiB @16
  unsigned short* wproj = (unsigned short*)(ws + (size_t)19 * 1048576);   //  2 MiB @19
  unsigned short* qkv   = (unsigned short*)(ws + (size_t)21 * 1048576);   // 96 MiB @21
  unsigned short* vT    = (unsigned short*)(ws + (size_t)117 * 1048576);  // 64 MiB @117
  float* out = (float*)d_out;                                             // fp32 output

  cvt_kernel<<<dim3(6144), dim3(256), 0, stream>>>(qkv_w, wqkv, 3072 * 512);
  cvt_kernel<<<dim3(4096), dim3(256), 0, stream>>>(proj_w, wproj, 512 * 2048);
  ln_kernel<<<dim3(16384), dim3(256), 0, stream>>>(x, gamma, beta, xn);
  gemm_gll<unsigned short, false><<<dim3(24, 128), dim3(256), 0, stream>>>(xn, 512, wqkv, 512, qkv_b, qkv, 3072, 512);
  transpose_v<<<dim3(16, 256), dim3(256), 0, stream>>>(qkv, vT);
  attn_kernel<<<dim3(4096), dim3(256), 0, stream>>>(qkv, vT, ab, qkv);
  gemm_gll<float, true><<<dim3(4, 128), dim3(256), 0, stream>>>(qkv, 3072, wproj, 2048, proj_b, out, 512, 2048);
}